// Round 4
// baseline (622.761 us; speedup 1.0000x reference)
//
#include <hip/hip_runtime.h>

// Problem: B=32, L=4, W=512, D=768, fp32.
// out = [word: B*D*W][sent: B*D]
// word[b][d][s] = (1/L) * sum_{w: seg[b][w]==s} sum_l emb[b][l][w][d]; gaps = 0
// sent[b][d]    = (1/(W*L)) * sum_{w,l} emb[b][l][w][d]
#define BB 32
#define LL 4
#define WW 512
#define DD 768
#define D4 (DD / 4)
#define WORD_SIZE (BB * DD * WW)
#define NCHUNK 64
#define WCHUNK (WW / NCHUNK)     // 8 words per chunk
#define TSTRIDE 772              // 768+4: float4-aligned, word shifts banks by 4

// ---------------------------------------------------------------------------
// prezero: zero sent + zero boundary-shared word columns (the only columns
// written purely by atomicAdd in `fused`). Grid: (B), block 256.
// ---------------------------------------------------------------------------
__global__ __launch_bounds__(256) void prezero(
    const int* __restrict__ seg, float* __restrict__ word, float* __restrict__ sent)
{
    const int b = blockIdx.x;
    const int tid = threadIdx.x;
    for (int d = tid; d < DD; d += 256) sent[(size_t)b * DD + d] = 0.f;

    __shared__ int srow[WW];
    for (int i = tid; i < WW; i += 256) srow[i] = seg[b * WW + i];
    __syncthreads();
    for (int j = 1; j < NCHUNK; ++j) {
        const int w = j * WCHUNK;
        if (srow[w - 1] == srow[w]) {
            const int s = srow[w];
            float* p = word + (size_t)b * DD * WW + s;
            for (int d = tid; d < DD; d += 256) p[(size_t)d * WW] = 0.f;
        }
    }
}

// ---------------------------------------------------------------------------
// fused: layer-mean per word -> LDS tile[8][772]; then per-column sums
// (contiguous word ranges, since seg is sorted) transposed straight into
// word[b][d][col] with zero-fill for owned gap columns. Boundary-shared
// columns (<=2 per block) go via atomicAdd onto prezeroed columns.
// Grid: (NCHUNK, B) = (64, 32). Block 192: thread t owns d = 4t..4t+3 in
// phase 1; (c = t&15, dr = t>>4) in phase 2. All branches block-uniform
// except the per-lane column loop (no syncs inside).
// ---------------------------------------------------------------------------
__global__ __launch_bounds__(192) void fused(
    const float* __restrict__ emb,   // [B, L, W, D]
    const int*   __restrict__ seg,   // [B, W] sorted per row
    float* __restrict__ word,        // [B, D, W]
    float* __restrict__ sent)        // [B, D] (pre-zeroed)
{
    const int b   = blockIdx.y;
    const int w0  = blockIdx.x * WCHUNK;
    const int tid = threadIdx.x;           // 0..191
    const int d   = tid * 4;

    __shared__ float tile[WCHUNK * TSTRIDE];   // 24704 B
    __shared__ int   seg_sh[WCHUNK];
    __shared__ int   nb2[2];
    __shared__ short wstart[WW];
    __shared__ short wcnt[WW];

    if (tid < WCHUNK) seg_sh[tid] = seg[b * WW + w0 + tid];
    if (tid == 190) nb2[0] = (blockIdx.x > 0)          ? seg[b * WW + w0 - 1]      : -1;
    if (tid == 191) nb2[1] = (blockIdx.x < NCHUNK - 1) ? seg[b * WW + w0 + WCHUNK] : -2;
    __syncthreads();

    const int  segL  = seg_sh[0];
    const int  segR  = seg_sh[WCHUNK - 1];
    const bool atomL = (nb2[0] == segL);
    const bool atomR = (nb2[1] == segR);
    // Owned/touched column range. By sortedness: cmin <= segL <= segR <= cmax.
    const int cmin = atomL ? segL : nb2[0] + 1;                 // block 0: 0
    const int cmax = (blockIdx.x == NCHUNK - 1) ? (WW - 1) : segR;
    const int len  = cmax - cmin + 1;                           // >= 1 always

    // ---- phase 1: layer-mean each word into its LDS row --------------------
    const float4* e4 = (const float4*)emb;
    const size_t base = (size_t)b * LL * WW * D4 + tid;
    const size_t lstr = (size_t)WW * D4;

    float4 sentacc = make_float4(0.f, 0.f, 0.f, 0.f);
    for (int wi = 0; wi < WCHUNK; ++wi) {
        const size_t off = base + (size_t)(w0 + wi) * D4;
        float4 t0 = e4[off];
        float4 t1 = e4[off + lstr];
        float4 t2 = e4[off + 2 * lstr];
        float4 t3 = e4[off + 3 * lstr];
        float4 t;
        t.x = (t0.x + t1.x) + (t2.x + t3.x);
        t.y = (t0.y + t1.y) + (t2.y + t3.y);
        t.z = (t0.z + t1.z) + (t2.z + t3.z);
        t.w = (t0.w + t1.w) + (t2.w + t3.w);
        sentacc.x += t.x; sentacc.y += t.y; sentacc.z += t.z; sentacc.w += t.w;
        t.x *= 0.25f; t.y *= 0.25f; t.z *= 0.25f; t.w *= 0.25f;   // layer mean
        *(float4*)&tile[wi * TSTRIDE + d] = t;
    }

    // sent: one atomic per (chunk, d); 64 contributors per target
    const float ss = 1.0f / (float)(WW * LL);
    float* sp = sent + (size_t)b * DD + d;
    atomicAdd(sp + 0, sentacc.x * ss);
    atomicAdd(sp + 1, sentacc.y * ss);
    atomicAdd(sp + 2, sentacc.z * ss);
    atomicAdd(sp + 3, sentacc.w * ss);

    // ---- phase 2: per-column word ranges, then transpose out ---------------
    for (int i = tid; i < len; i += 192) { wcnt[i] = 0; wstart[i] = 0; }
    __syncthreads();                       // tile + wcnt-init visible
    if (tid == 0) {
        for (int w = 0; w < WCHUNK; ++w) { // seg_sh sorted: ranges contiguous
            const int idx = seg_sh[w] - cmin;      // in [0, len)
            if (wcnt[idx] == 0) wstart[idx] = (short)w;
            wcnt[idx]++;
        }
    }
    __syncthreads();

    float* wbase = word + (size_t)b * DD * WW;
    const int c  = tid & 15;               // column within 16-group
    const int dr = tid >> 4;               // 0..11

    for (int g = 0; g < len; g += 16) {
        const int ci = g + c;
        if (ci >= len) continue;
        const int col = cmin + ci;
        const int cnt = wcnt[ci];
        const int ws0 = wstart[ci];
        const bool isAtomic = (col == segL && atomL) || (col == segR && atomR);
        float* outp = wbase + col;
        for (int dd = dr; dd < DD; dd += 12) {
            float v = 0.f;
            for (int j = 0; j < cnt; ++j) v += tile[(ws0 + j) * TSTRIDE + dd];
            if (isAtomic) atomicAdd(outp + (size_t)dd * WW, v);
            else          outp[(size_t)dd * WW] = v;
        }
    }
}

extern "C" void kernel_launch(void* const* d_in, const int* in_sizes, int n_in,
                              void* d_out, int out_size, void* d_ws, size_t ws_size,
                              hipStream_t stream) {
    const float* emb = (const float*)d_in[0];   // [32,4,512,768] fp32
    const int*   seg = (const int*)d_in[1];     // [32,512] int32, sorted per row
    float* out  = (float*)d_out;
    float* word = out;                          // [B, D, W]
    float* sent = out + WORD_SIZE;              // [B, D]

    prezero<<<dim3(BB), dim3(256), 0, stream>>>(seg, word, sent);
    fused<<<dim3(NCHUNK, BB), dim3(192), 0, stream>>>(emb, seg, word, sent);
}